// Round 6
// baseline (411.626 us; speedup 1.0000x reference)
//
#include <hip/hip_runtime.h>
#include <hip/hip_bf16.h>
#include <math.h>

// ---------------------------------------------------------------------------
// GAT: 2x GATConv(heads=1) + global mean pool + FC(64->2)
// R19 = R17 (best, 331.0us) + two changes:
//  (1) aggregate pipeline depth 4 -> 8 (8 gathers in flight per lane) at
//      R17's PROVEN geometry (8 lanes/node, 32 nodes/block, 3125 blocks,
//      8 blocks/CU). Tests the MLP model: BW ~ waves/CU x depth.
//      R18 evidence: 24 w/CU x4 -> 2.94 TB/s; R17: 32 w/CU x4 -> 3.58.
//      Depth 8 at 32 w/CU predicts ~5 TB/s -> agg ~40us.
//  (2) L2 aggregate fuses mean-pool: POOL template accumulates per-graph
//      sums (wave shuffle + LDS + 64 global atomics/block) into gsum[256][64]
//      instead of writing 25.6MB hout; pool_fc becomes a 64KB-read FC.
// CSR build (fused src-sort), gemm unchanged from R17.
// (Resubmission of R19: previous round failed with GPUAcquisitionTimeout
//  before the kernel ever ran.)
// ---------------------------------------------------------------------------

#define NPB 256          // nodes per bucket
#define EPB 4096         // edges per partition block (256 thr x 16)
#define PSTRIDE 4608     // slots per bucket (lambda=4092, +8 sigma)
#define XPAD 68          // xs leading-dim pad: 8-way banks, 16B-aligned rows

__device__ __forceinline__ unsigned int f2bf(float v) {
    unsigned int b = __float_as_uint(v);
    b += 0x7FFFu + ((b >> 16) & 1u);   // round-to-nearest-even
    return b >> 16;
}

// --- init: zero bucket cursors + per-graph sums -----------------------------
__global__ __launch_bounds__(256) void init_all(int* __restrict__ bcur, int NB,
                                                float* __restrict__ gsum, int M) {
    int i = blockIdx.x * 256 + threadIdx.x;
    if (i < NB) bcur[i] = 0;
    if (i < M) gsum[i] = 0.0f;
}

// --- partition edges into fixed-stride dst-buckets (packed uint32) ----------
__global__ __launch_bounds__(256) void partition(const int* __restrict__ ei,
                                                 int E, int NB,
                                                 int* __restrict__ bcur,
                                                 unsigned int* __restrict__ pairs) {
    __shared__ int h[512];
    __shared__ int hb[512];
    int t = threadIdx.x;
    for (int i = t; i < 512; i += 256) h[i] = 0;
    __syncthreads();
    int i0 = blockIdx.x * EPB;
    unsigned int val[16];
    int bk[16], r[16];
#pragma unroll
    for (int k = 0; k < 16; k++) {
        int i = i0 + k * 256 + t;
        bk[k] = -1;
        if (i < E) {
            int s = ei[i];
            int d = ei[E + i];
            bk[k] = d >> 8;
            val[k] = (unsigned)s | ((unsigned)(d & 255) << 24);
            r[k] = atomicAdd(&h[bk[k]], 1);
        }
    }
    __syncthreads();
    for (int b = t; b < NB; b += 256)
        hb[b] = h[b] ? atomicAdd(&bcur[b], h[b]) : 0;
    __syncthreads();
#pragma unroll
    for (int k = 0; k < 16; k++) {
        if (bk[k] < 0) continue;
        int pos = hb[bk[k]] + r[k];
        if (pos < PSTRIDE)                 // overflow guard (stat. impossible)
            pairs[(size_t)bk[k] * PSTRIDE + pos] = val[k];
    }
}

// --- per-bucket CSR fill with FUSED counting sort by src>>9 -----------------
__global__ __launch_bounds__(256) void build_csr(const unsigned int* __restrict__ pairs,
                                                 const int* __restrict__ bcur,
                                                 int n, int NB,
                                                 int* __restrict__ rowptr,
                                                 int* __restrict__ srcs) {
    int b = blockIdx.x, t = threadIdx.x;
    __shared__ int c[512];
    __shared__ int s2[256];
    __shared__ int sbase, stot;
    __shared__ unsigned int Q[PSTRIDE];   // 18.4 KB sorted bucket
    __shared__ int hist[256];
    __shared__ int hcur[256];
    // ---- global bucket-count scan (for CSR base offset) ----
    int c0 = (2 * t < NB) ? min(bcur[2 * t], PSTRIDE) : 0;
    int c1 = (2 * t + 1 < NB) ? min(bcur[2 * t + 1], PSTRIDE) : 0;
    c[2 * t] = c0; c[2 * t + 1] = c1;
    s2[t] = c0 + c1;
    hist[t] = 0;
    __syncthreads();
    for (int o = 1; o < 256; o <<= 1) {
        int u = (t >= o) ? s2[t - o] : 0;
        __syncthreads();
        s2[t] += u;
        __syncthreads();
    }
    if (t == 0) {
        int p = b >> 1;
        int ex = s2[p] - (c[2 * p] + c[2 * p + 1]);
        sbase = ex + ((b & 1) ? c[b & ~1] : 0);
        stot = s2[255];
    }
    __syncthreads();
    int d0 = b << 8;
    int nb = min(NPB, n - d0);
    int cnt_b = c[b];
    int csr0 = sbase + d0;   // pairs before + one self-loop per node before
    const unsigned int* pb = pairs + (size_t)b * PSTRIDE;

    // ---- counting sort by src>>9 into Q ----
    for (int j = t; j < cnt_b; j += 256)
        atomicAdd(&hist[(pb[j] & 0xFFFFFFu) >> 9], 1);   // key <= 195
    __syncthreads();
    int hv = hist[t];
    hcur[t] = hv;
    __syncthreads();
    for (int o = 1; o < 256; o <<= 1) {
        int u = (t >= o) ? hcur[t - o] : 0;
        __syncthreads();
        hcur[t] += u;
        __syncthreads();
    }
    hcur[t] -= hv;                        // exclusive base -> cursor
    __syncthreads();
    for (int j = t; j < cnt_b; j += 256) {
        unsigned int p = pb[j];
        int pos = atomicAdd(&hcur[(p & 0xFFFFFFu) >> 9], 1);
        Q[pos] = p;
    }
    __syncthreads();

    // ---- degree count / scan / fill from sorted Q ----
    __shared__ int deg[NPB];
    __shared__ int cur[NPB];
    __shared__ int tmp[NPB];
    deg[t] = (t < nb) ? 1 : 0;   // self-loop
    __syncthreads();
    for (int j = t; j < cnt_b; j += 256)
        atomicAdd(&deg[Q[j] >> 24], 1);
    __syncthreads();
    int v = deg[t];
    tmp[t] = v;
    __syncthreads();
    for (int o = 1; o < NPB; o <<= 1) {
        int u = (t >= o) ? tmp[t - o] : 0;
        __syncthreads();
        tmp[t] += u;
        __syncthreads();
    }
    int excl = tmp[t] - v;
    if (t < nb) {
        rowptr[d0 + t] = csr0 + excl;
        srcs[csr0 + excl] = d0 + t;   // self-loop at slot 0
        cur[t] = excl + 1;
    }
    __syncthreads();
    // j-round order over sorted Q -> each node's list fills ~ascending in src
    for (int j = t; j < cnt_b; j += 256) {
        unsigned int p = Q[j];
        int off = atomicAdd(&cur[p >> 24], 1);
        srcs[csr0 + off] = (int)(p & 0x00FFFFFFu);
    }
    if (b == 0 && t == 0) rowptr[n] = n + stot;
}

// --- tiled node GEMM: 64 nodes x 64 cols per block, 4x4 per thread ----------
template <int IN_DIM>
__global__ __launch_bounds__(256) void node_gemm(const float* __restrict__ x,
                                                 const float* __restrict__ W,
                                                 const float* __restrict__ a_src,
                                                 const float* __restrict__ a_dst,
                                                 const float* __restrict__ bias_in,
                                                 float slope_in,
                                                 unsigned short* __restrict__ h16,
                                                 float* __restrict__ al_s,
                                                 float* __restrict__ al_d,
                                                 int n) {
    __shared__ float Ws[IN_DIM * 64];
    __shared__ float xs[IN_DIM][XPAD];
    int t = threadIdx.x;
    int nbase = blockIdx.x * 64;

    for (int idx = t; idx < IN_DIM * 16; idx += 256)
        ((float4*)Ws)[idx] = ((const float4*)W)[idx];
    const float* xb = x + (size_t)nbase * IN_DIM;
    int lim = min(64, n - nbase) * IN_DIM;
    for (int idx = t; idx < 64 * IN_DIM; idx += 256) {
        int node = idx / IN_DIM;
        int k = idx - node * IN_DIM;
        float v = 0.0f;
        if (idx < lim) {
            v = xb[idx];                       // contiguous, fully coalesced
            if (bias_in) {
                v += bias_in[k];
                v = (v >= 0.0f) ? v : slope_in * v;
            }
        }
        xs[k][node] = v;
    }
    __syncthreads();

    int cg = t & 15;    // col group: cols 4cg..4cg+3
    int ng = t >> 4;    // node group: nodes 4ng..4ng+3
    float acc[4][4] = {};
#pragma unroll 8
    for (int k = 0; k < IN_DIM; k++) {
        float4 xv = *(const float4*)&xs[k][ng * 4];
        float4 wv = *(const float4*)&Ws[k * 64 + cg * 4];
        float xa[4] = {xv.x, xv.y, xv.z, xv.w};
        float wa[4] = {wv.x, wv.y, wv.z, wv.w};
#pragma unroll
        for (int i = 0; i < 4; i++)
#pragma unroll
            for (int j = 0; j < 4; j++)
                acc[i][j] += xa[i] * wa[j];
    }

    float4 as4 = *(const float4*)(a_src + cg * 4);
    float4 ad4 = *(const float4*)(a_dst + cg * 4);
#pragma unroll
    for (int i = 0; i < 4; i++) {
        int node = nbase + ng * 4 + i;
        if (node < n) {
            uint2 p;
            p.x = f2bf(acc[i][0]) | (f2bf(acc[i][1]) << 16);
            p.y = f2bf(acc[i][2]) | (f2bf(acc[i][3]) << 16);
            *(uint2*)(h16 + (size_t)node * 64 + cg * 4) = p;
        }
        float vs = acc[i][0] * as4.x + acc[i][1] * as4.y +
                   acc[i][2] * as4.z + acc[i][3] * as4.w;
        float vd = acc[i][0] * ad4.x + acc[i][1] * ad4.y +
                   acc[i][2] * ad4.z + acc[i][3] * ad4.w;
#pragma unroll
        for (int o = 8; o; o >>= 1) {
            vs += __shfl_xor(vs, o);
            vd += __shfl_xor(vd, o);
        }
        if (cg == 0 && node < n) { al_s[node] = vs; al_d[node] = vd; }
    }
}

// --- single-pass aggregate: 8 lanes/node, depth-8 pipeline ------------------
// out[node] = (sum_j exp(e_j)*h[src_j]) / (sum_j exp(e_j) + 1e-16)
// POOL variant: reduce out rows into per-graph sums gsum[G][64] (mean-pool
// fusion); non-POOL writes hout rows.
__device__ __forceinline__ void bf8_fma(float* acc, uint4 q, float w) {
    acc[0] += w * __uint_as_float(q.x << 16);
    acc[1] += w * __uint_as_float(q.x & 0xFFFF0000u);
    acc[2] += w * __uint_as_float(q.y << 16);
    acc[3] += w * __uint_as_float(q.y & 0xFFFF0000u);
    acc[4] += w * __uint_as_float(q.z << 16);
    acc[5] += w * __uint_as_float(q.z & 0xFFFF0000u);
    acc[6] += w * __uint_as_float(q.w << 16);
    acc[7] += w * __uint_as_float(q.w & 0xFFFF0000u);
}

template <bool POOL>
__global__ __launch_bounds__(256, 8) void gat_aggregate(const int* __restrict__ rowptr,
                                                        const int* __restrict__ srcs,
                                                        const float* __restrict__ als,
                                                        const float* __restrict__ ald,
                                                        const unsigned short* __restrict__ h16,
                                                        float* __restrict__ hout,
                                                        float* __restrict__ gsum,
                                                        const int* __restrict__ batch,
                                                        int n) {
    int t = threadIdx.x;
    int sub = t >> 3, lane = t & 7;       // 32 nodes/block, 8 lanes/node
    int node = blockIdx.x * 32 + sub;
    bool act = node < n;
    int beg = 0, end = 0;
    float aldv = 0.0f;
    if (act) { beg = rowptr[node]; end = rowptr[node + 1]; aldv = ald[node]; }
    const unsigned short* hb = h16 + lane * 8;

    float acc[8] = {};
    float sm = 0.0f;
    int j = beg;
    // depth-8 main loop: 8 independent gathers in flight per lane
    for (; j + 8 <= end; j += 8) {
        int s0 = srcs[j],     s1 = srcs[j + 1], s2 = srcs[j + 2], s3 = srcs[j + 3];
        int s4 = srcs[j + 4], s5 = srcs[j + 5], s6 = srcs[j + 6], s7 = srcs[j + 7];
        uint4 q0 = *(const uint4*)(hb + (size_t)s0 * 64);
        uint4 q1 = *(const uint4*)(hb + (size_t)s1 * 64);
        uint4 q2 = *(const uint4*)(hb + (size_t)s2 * 64);
        uint4 q3 = *(const uint4*)(hb + (size_t)s3 * 64);
        uint4 q4 = *(const uint4*)(hb + (size_t)s4 * 64);
        uint4 q5 = *(const uint4*)(hb + (size_t)s5 * 64);
        uint4 q6 = *(const uint4*)(hb + (size_t)s6 * 64);
        uint4 q7 = *(const uint4*)(hb + (size_t)s7 * 64);
        float e0 = als[s0] + aldv, e1 = als[s1] + aldv;
        float e2 = als[s2] + aldv, e3 = als[s3] + aldv;
        float e4 = als[s4] + aldv, e5 = als[s5] + aldv;
        float e6 = als[s6] + aldv, e7 = als[s7] + aldv;
        e0 = (e0 >= 0.0f) ? e0 : 0.2f * e0;
        e1 = (e1 >= 0.0f) ? e1 : 0.2f * e1;
        e2 = (e2 >= 0.0f) ? e2 : 0.2f * e2;
        e3 = (e3 >= 0.0f) ? e3 : 0.2f * e3;
        e4 = (e4 >= 0.0f) ? e4 : 0.2f * e4;
        e5 = (e5 >= 0.0f) ? e5 : 0.2f * e5;
        e6 = (e6 >= 0.0f) ? e6 : 0.2f * e6;
        e7 = (e7 >= 0.0f) ? e7 : 0.2f * e7;
        float w0 = __expf(e0), w1 = __expf(e1);
        float w2 = __expf(e2), w3 = __expf(e3);
        float w4 = __expf(e4), w5 = __expf(e5);
        float w6 = __expf(e6), w7 = __expf(e7);
        sm += ((w0 + w1) + (w2 + w3)) + ((w4 + w5) + (w6 + w7));
        bf8_fma(acc, q0, w0);
        bf8_fma(acc, q1, w1);
        bf8_fma(acc, q2, w2);
        bf8_fma(acc, q3, w3);
        bf8_fma(acc, q4, w4);
        bf8_fma(acc, q5, w5);
        bf8_fma(acc, q6, w6);
        bf8_fma(acc, q7, w7);
    }
    // quad tail
    for (; j + 4 <= end; j += 4) {
        int s0 = srcs[j], s1 = srcs[j + 1], s2 = srcs[j + 2], s3 = srcs[j + 3];
        uint4 q0 = *(const uint4*)(hb + (size_t)s0 * 64);
        uint4 q1 = *(const uint4*)(hb + (size_t)s1 * 64);
        uint4 q2 = *(const uint4*)(hb + (size_t)s2 * 64);
        uint4 q3 = *(const uint4*)(hb + (size_t)s3 * 64);
        float e0 = als[s0] + aldv, e1 = als[s1] + aldv;
        float e2 = als[s2] + aldv, e3 = als[s3] + aldv;
        e0 = (e0 >= 0.0f) ? e0 : 0.2f * e0;
        e1 = (e1 >= 0.0f) ? e1 : 0.2f * e1;
        e2 = (e2 >= 0.0f) ? e2 : 0.2f * e2;
        e3 = (e3 >= 0.0f) ? e3 : 0.2f * e3;
        float w0 = __expf(e0), w1 = __expf(e1);
        float w2 = __expf(e2), w3 = __expf(e3);
        sm += (w0 + w1) + (w2 + w3);
        bf8_fma(acc, q0, w0);
        bf8_fma(acc, q1, w1);
        bf8_fma(acc, q2, w2);
        bf8_fma(acc, q3, w3);
    }
    for (; j < end; j++) {
        int s = srcs[j];
        float e = als[s] + aldv;
        e = (e >= 0.0f) ? e : 0.2f * e;
        float w = __expf(e);
        uint4 q = *(const uint4*)(hb + (size_t)s * 64);
        sm += w;
        bf8_fma(acc, q, w);
    }

    float inv = 1.0f / (sm + 1e-16f);
    if (!POOL) {
        if (act) {
            float* op = hout + (size_t)node * 64 + lane * 8;
            *(float4*)op = make_float4(acc[0] * inv, acc[1] * inv, acc[2] * inv, acc[3] * inv);
            *(float4*)(op + 4) = make_float4(acc[4] * inv, acc[5] * inv, acc[6] * inv, acc[7] * inv);
        }
    } else {
        float o[8];
#pragma unroll
        for (int k = 0; k < 8; k++) o[k] = act ? acc[k] * inv : 0.0f;
        int d0 = blockIdx.x * 32;
        int gF = batch[d0];                               // d0 < n for all blocks
        int gL = batch[(d0 + 31 < n) ? d0 + 31 : n - 1];
        __shared__ float red[4][64];
        if (gF == gL) {
            // uniform block: shuffle-reduce across the wave's 8 subs
#pragma unroll
            for (int k = 0; k < 8; k++) {
                o[k] += __shfl_xor(o[k], 8);
                o[k] += __shfl_xor(o[k], 16);
                o[k] += __shfl_xor(o[k], 32);
            }
            int wv = t >> 6;
            if ((t & 56) == 0) {                          // one sub per wave holds sums
#pragma unroll
                for (int k = 0; k < 8; k++) red[wv][lane * 8 + k] = o[k];
            }
            __syncthreads();
            if (t < 64) {
                float s = red[0][t] + red[1][t] + red[2][t] + red[3][t];
                atomicAdd(&gsum[gF * 64 + t], s);
            }
        } else {
            // graph-boundary block (~8%): per-thread global atomics
            int myg = act ? batch[node] : gF;
#pragma unroll
            for (int k = 0; k < 8; k++)
                atomicAdd(&gsum[myg * 64 + lane * 8 + k], o[k]);
        }
    }
}

// --- tiny FC over fused per-graph sums: one wave per graph ------------------
__global__ __launch_bounds__(64) void fc_small(const float* __restrict__ gsum,
                                               const float* __restrict__ b2,
                                               const int* __restrict__ batch,
                                               const float* __restrict__ fcW,
                                               const float* __restrict__ fcb,
                                               float* __restrict__ out, int n) {
    int g = blockIdx.x;
    int t = threadIdx.x;   // 0..63
    __shared__ int sLo, sHi;
    if (t == 0) {
        int lo = 0, hi = n;
        while (lo < hi) { int m = (lo + hi) >> 1; if (batch[m] < g) lo = m + 1; else hi = m; }
        sLo = lo;
    } else if (t == 1) {
        int lo = 0, hi = n;
        while (lo < hi) { int m = (lo + hi) >> 1; if (batch[m] < g + 1) lo = m + 1; else hi = m; }
        sHi = lo;
    }
    __syncthreads();
    float c = (float)(sHi - sLo);
    float s = gsum[g * 64 + t] + c * b2[t];
    float cd = (c > 1.0f) ? c : 1.0f;
    float p = s / cd;
    float s0 = p * fcW[t * 2 + 0];
    float s1 = p * fcW[t * 2 + 1];
#pragma unroll
    for (int o = 32; o; o >>= 1) {
        s0 += __shfl_xor(s0, o);
        s1 += __shfl_xor(s1, o);
    }
    if (t == 0) {
        out[g * 2 + 0] = s0 + fcb[0];
        out[g * 2 + 1] = s1 + fcb[1];
    }
}

extern "C" void kernel_launch(void* const* d_in, const int* in_sizes, int n_in,
                              void* d_out, int out_size, void* d_ws, size_t ws_size,
                              hipStream_t stream) {
    const float* x    = (const float*)d_in[0];
    const int*   ei   = (const int*)d_in[1];
    const int*   batch= (const int*)d_in[2];
    const float* W1   = (const float*)d_in[3];
    const float* as1  = (const float*)d_in[4];
    const float* ad1  = (const float*)d_in[5];
    const float* b1   = (const float*)d_in[6];
    const float* W2   = (const float*)d_in[7];
    const float* as2  = (const float*)d_in[8];
    const float* ad2  = (const float*)d_in[9];
    const float* b2   = (const float*)d_in[10];
    const float* fcW  = (const float*)d_in[11];
    const float* fcb  = (const float*)d_in[12];
    float* out = (float*)d_out;

    const int N = in_sizes[2];       // 100000
    const int E = in_sizes[1] / 2;   // 1600000
    const int G = out_size / 2;      // 256
    const int tot = E + N;
    const int NB = (N + NPB - 1) / NPB;   // 391 buckets

    // ws layout (~46.5 MiB): pairs ALIASES bufO (disjoint lifetimes:
    // pairs die at build_csr; bufO first written by aggregate layer 1).
    float* ws     = (float*)d_ws;
    float* bufO   = ws;                                  // N*64 fp32  25.6 MB
    unsigned int* pairs  = (unsigned int*)bufO;          // alias      7.2 MB
    float* als    = bufO + (size_t)N * 64;               // N          0.4 MB
    float* ald    = als + N;                             // N          0.4 MB
    int*   rowptr = (int*)(ald + N);                     // N+1        0.4 MB
    int*   srcs   = rowptr + N + 1;                      // tot        6.8 MB
    int*   bcur   = srcs + tot;                          // NB
    unsigned short* bufH16 = (unsigned short*)(bcur + NB);  // N*64   12.8 MB
    float* gsum   = (float*)(bufH16 + (size_t)N * 64);   // G*64       64 KB

    dim3 b256(256);
    int gsElems = G * 64;
    int gInit = (max(NB, gsElems) + 255) / 256;
    int gPart = (E + EPB - 1) / EPB;
    int gGemm = (N + 63) / 64;
    int gAgg  = (N + 31) / 32;

    // ---- CSR build: partition + fused sort/fill -----------------------------
    init_all<<<gInit, b256, 0, stream>>>(bcur, NB, gsum, gsElems);
    partition<<<gPart, b256, 0, stream>>>(ei, E, NB, bcur, pairs);
    build_csr<<<NB, b256, 0, stream>>>(pairs, bcur, N, NB, rowptr, srcs);

    // ---- layer 1 ----
    node_gemm<72><<<gGemm, b256, 0, stream>>>(x, W1, as1, ad1, nullptr, 0.0f,
                                              bufH16, als, ald, N);
    gat_aggregate<false><<<gAgg, b256, 0, stream>>>(rowptr, srcs, als, ald,
                                                    bufH16, bufO, nullptr, nullptr, N);

    // ---- layer 2 (input = leaky(bufO + b1, 0.01)); pool fused in -----------
    node_gemm<64><<<gGemm, b256, 0, stream>>>(bufO, W2, as2, ad2, b1, 0.01f,
                                              bufH16, als, ald, N);
    gat_aggregate<true><<<gAgg, b256, 0, stream>>>(rowptr, srcs, als, ald,
                                                   bufH16, nullptr, gsum, batch, N);

    // ---- tiny FC over per-graph sums ----
    fc_small<<<G, dim3(64), 0, stream>>>(gsum, b2, batch, fcW, fcb, out, N);
}

// Round 7
// 353.741 us; speedup vs baseline: 1.1636x; 1.1636x over previous
//
#include <hip/hip_runtime.h>
#include <hip/hip_bf16.h>
#include <math.h>

// ---------------------------------------------------------------------------
// GAT: 2x GATConv(heads=1) + global mean pool + FC(64->2)
// R20 = R17 aggregate loop (proven: depth-4 prefetch, 53.4us, 32 VGPR,
//       no spill) + R19's pool fusion ONLY.
//   R19 post-mortem: depth-8 loop spilled q-registers to scratch under the
//   64-VGPR/8-block cap (WRITE 25->95MB, FETCH +47MB, VALU 12.6%, 132us).
//   Depth lever is dead at this occupancy; depth-4 is the ceiling.
//   Pool fusion (POOL template epilogue writes per-graph sums instead of
//   25.6MB hout; tiny fc_small kernel) was not implicated -- kept.
// CSR build (fused src-sort), gemm unchanged from R17.
// ---------------------------------------------------------------------------

#define NPB 256          // nodes per bucket
#define EPB 4096         // edges per partition block (256 thr x 16)
#define PSTRIDE 4608     // slots per bucket (lambda=4092, +8 sigma)
#define XPAD 68          // xs leading-dim pad: 8-way banks, 16B-aligned rows

__device__ __forceinline__ unsigned int f2bf(float v) {
    unsigned int b = __float_as_uint(v);
    b += 0x7FFFu + ((b >> 16) & 1u);   // round-to-nearest-even
    return b >> 16;
}

// --- init: zero bucket cursors + per-graph sums -----------------------------
__global__ __launch_bounds__(256) void init_all(int* __restrict__ bcur, int NB,
                                                float* __restrict__ gsum, int M) {
    int i = blockIdx.x * 256 + threadIdx.x;
    if (i < NB) bcur[i] = 0;
    if (i < M) gsum[i] = 0.0f;
}

// --- partition edges into fixed-stride dst-buckets (packed uint32) ----------
__global__ __launch_bounds__(256) void partition(const int* __restrict__ ei,
                                                 int E, int NB,
                                                 int* __restrict__ bcur,
                                                 unsigned int* __restrict__ pairs) {
    __shared__ int h[512];
    __shared__ int hb[512];
    int t = threadIdx.x;
    for (int i = t; i < 512; i += 256) h[i] = 0;
    __syncthreads();
    int i0 = blockIdx.x * EPB;
    unsigned int val[16];
    int bk[16], r[16];
#pragma unroll
    for (int k = 0; k < 16; k++) {
        int i = i0 + k * 256 + t;
        bk[k] = -1;
        if (i < E) {
            int s = ei[i];
            int d = ei[E + i];
            bk[k] = d >> 8;
            val[k] = (unsigned)s | ((unsigned)(d & 255) << 24);
            r[k] = atomicAdd(&h[bk[k]], 1);
        }
    }
    __syncthreads();
    for (int b = t; b < NB; b += 256)
        hb[b] = h[b] ? atomicAdd(&bcur[b], h[b]) : 0;
    __syncthreads();
#pragma unroll
    for (int k = 0; k < 16; k++) {
        if (bk[k] < 0) continue;
        int pos = hb[bk[k]] + r[k];
        if (pos < PSTRIDE)                 // overflow guard (stat. impossible)
            pairs[(size_t)bk[k] * PSTRIDE + pos] = val[k];
    }
}

// --- per-bucket CSR fill with FUSED counting sort by src>>9 -----------------
__global__ __launch_bounds__(256) void build_csr(const unsigned int* __restrict__ pairs,
                                                 const int* __restrict__ bcur,
                                                 int n, int NB,
                                                 int* __restrict__ rowptr,
                                                 int* __restrict__ srcs) {
    int b = blockIdx.x, t = threadIdx.x;
    __shared__ int c[512];
    __shared__ int s2[256];
    __shared__ int sbase, stot;
    __shared__ unsigned int Q[PSTRIDE];   // 18.4 KB sorted bucket
    __shared__ int hist[256];
    __shared__ int hcur[256];
    // ---- global bucket-count scan (for CSR base offset) ----
    int c0 = (2 * t < NB) ? min(bcur[2 * t], PSTRIDE) : 0;
    int c1 = (2 * t + 1 < NB) ? min(bcur[2 * t + 1], PSTRIDE) : 0;
    c[2 * t] = c0; c[2 * t + 1] = c1;
    s2[t] = c0 + c1;
    hist[t] = 0;
    __syncthreads();
    for (int o = 1; o < 256; o <<= 1) {
        int u = (t >= o) ? s2[t - o] : 0;
        __syncthreads();
        s2[t] += u;
        __syncthreads();
    }
    if (t == 0) {
        int p = b >> 1;
        int ex = s2[p] - (c[2 * p] + c[2 * p + 1]);
        sbase = ex + ((b & 1) ? c[b & ~1] : 0);
        stot = s2[255];
    }
    __syncthreads();
    int d0 = b << 8;
    int nb = min(NPB, n - d0);
    int cnt_b = c[b];
    int csr0 = sbase + d0;   // pairs before + one self-loop per node before
    const unsigned int* pb = pairs + (size_t)b * PSTRIDE;

    // ---- counting sort by src>>9 into Q ----
    for (int j = t; j < cnt_b; j += 256)
        atomicAdd(&hist[(pb[j] & 0xFFFFFFu) >> 9], 1);   // key <= 195
    __syncthreads();
    int hv = hist[t];
    hcur[t] = hv;
    __syncthreads();
    for (int o = 1; o < 256; o <<= 1) {
        int u = (t >= o) ? hcur[t - o] : 0;
        __syncthreads();
        hcur[t] += u;
        __syncthreads();
    }
    hcur[t] -= hv;                        // exclusive base -> cursor
    __syncthreads();
    for (int j = t; j < cnt_b; j += 256) {
        unsigned int p = pb[j];
        int pos = atomicAdd(&hcur[(p & 0xFFFFFFu) >> 9], 1);
        Q[pos] = p;
    }
    __syncthreads();

    // ---- degree count / scan / fill from sorted Q ----
    __shared__ int deg[NPB];
    __shared__ int cur[NPB];
    __shared__ int tmp[NPB];
    deg[t] = (t < nb) ? 1 : 0;   // self-loop
    __syncthreads();
    for (int j = t; j < cnt_b; j += 256)
        atomicAdd(&deg[Q[j] >> 24], 1);
    __syncthreads();
    int v = deg[t];
    tmp[t] = v;
    __syncthreads();
    for (int o = 1; o < NPB; o <<= 1) {
        int u = (t >= o) ? tmp[t - o] : 0;
        __syncthreads();
        tmp[t] += u;
        __syncthreads();
    }
    int excl = tmp[t] - v;
    if (t < nb) {
        rowptr[d0 + t] = csr0 + excl;
        srcs[csr0 + excl] = d0 + t;   // self-loop at slot 0
        cur[t] = excl + 1;
    }
    __syncthreads();
    // j-round order over sorted Q -> each node's list fills ~ascending in src
    for (int j = t; j < cnt_b; j += 256) {
        unsigned int p = Q[j];
        int off = atomicAdd(&cur[p >> 24], 1);
        srcs[csr0 + off] = (int)(p & 0x00FFFFFFu);
    }
    if (b == 0 && t == 0) rowptr[n] = n + stot;
}

// --- tiled node GEMM: 64 nodes x 64 cols per block, 4x4 per thread ----------
template <int IN_DIM>
__global__ __launch_bounds__(256) void node_gemm(const float* __restrict__ x,
                                                 const float* __restrict__ W,
                                                 const float* __restrict__ a_src,
                                                 const float* __restrict__ a_dst,
                                                 const float* __restrict__ bias_in,
                                                 float slope_in,
                                                 unsigned short* __restrict__ h16,
                                                 float* __restrict__ al_s,
                                                 float* __restrict__ al_d,
                                                 int n) {
    __shared__ float Ws[IN_DIM * 64];
    __shared__ float xs[IN_DIM][XPAD];
    int t = threadIdx.x;
    int nbase = blockIdx.x * 64;

    for (int idx = t; idx < IN_DIM * 16; idx += 256)
        ((float4*)Ws)[idx] = ((const float4*)W)[idx];
    const float* xb = x + (size_t)nbase * IN_DIM;
    int lim = min(64, n - nbase) * IN_DIM;
    for (int idx = t; idx < 64 * IN_DIM; idx += 256) {
        int node = idx / IN_DIM;
        int k = idx - node * IN_DIM;
        float v = 0.0f;
        if (idx < lim) {
            v = xb[idx];                       // contiguous, fully coalesced
            if (bias_in) {
                v += bias_in[k];
                v = (v >= 0.0f) ? v : slope_in * v;
            }
        }
        xs[k][node] = v;
    }
    __syncthreads();

    int cg = t & 15;    // col group: cols 4cg..4cg+3
    int ng = t >> 4;    // node group: nodes 4ng..4ng+3
    float acc[4][4] = {};
#pragma unroll 8
    for (int k = 0; k < IN_DIM; k++) {
        float4 xv = *(const float4*)&xs[k][ng * 4];
        float4 wv = *(const float4*)&Ws[k * 64 + cg * 4];
        float xa[4] = {xv.x, xv.y, xv.z, xv.w};
        float wa[4] = {wv.x, wv.y, wv.z, wv.w};
#pragma unroll
        for (int i = 0; i < 4; i++)
#pragma unroll
            for (int j = 0; j < 4; j++)
                acc[i][j] += xa[i] * wa[j];
    }

    float4 as4 = *(const float4*)(a_src + cg * 4);
    float4 ad4 = *(const float4*)(a_dst + cg * 4);
#pragma unroll
    for (int i = 0; i < 4; i++) {
        int node = nbase + ng * 4 + i;
        if (node < n) {
            uint2 p;
            p.x = f2bf(acc[i][0]) | (f2bf(acc[i][1]) << 16);
            p.y = f2bf(acc[i][2]) | (f2bf(acc[i][3]) << 16);
            *(uint2*)(h16 + (size_t)node * 64 + cg * 4) = p;
        }
        float vs = acc[i][0] * as4.x + acc[i][1] * as4.y +
                   acc[i][2] * as4.z + acc[i][3] * as4.w;
        float vd = acc[i][0] * ad4.x + acc[i][1] * ad4.y +
                   acc[i][2] * ad4.z + acc[i][3] * ad4.w;
#pragma unroll
        for (int o = 8; o; o >>= 1) {
            vs += __shfl_xor(vs, o);
            vd += __shfl_xor(vd, o);
        }
        if (cg == 0 && node < n) { al_s[node] = vs; al_d[node] = vd; }
    }
}

// --- single-pass aggregate (R17 proven loop): 8 lanes/node, depth-4 ---------
// out[node] = (sum_j exp(e_j)*h[src_j]) / (sum_j exp(e_j) + 1e-16)
// POOL variant: reduce rows into per-graph sums gsum[G][64] (mean-pool
// fusion); non-POOL writes hout rows.
__device__ __forceinline__ void bf8_fma(float* acc, uint4 q, float w) {
    acc[0] += w * __uint_as_float(q.x << 16);
    acc[1] += w * __uint_as_float(q.x & 0xFFFF0000u);
    acc[2] += w * __uint_as_float(q.y << 16);
    acc[3] += w * __uint_as_float(q.y & 0xFFFF0000u);
    acc[4] += w * __uint_as_float(q.z << 16);
    acc[5] += w * __uint_as_float(q.z & 0xFFFF0000u);
    acc[6] += w * __uint_as_float(q.w << 16);
    acc[7] += w * __uint_as_float(q.w & 0xFFFF0000u);
}

template <bool POOL>
__global__ __launch_bounds__(256, 8) void gat_aggregate(const int* __restrict__ rowptr,
                                                        const int* __restrict__ srcs,
                                                        const float* __restrict__ als,
                                                        const float* __restrict__ ald,
                                                        const unsigned short* __restrict__ h16,
                                                        float* __restrict__ hout,
                                                        float* __restrict__ gsum,
                                                        const int* __restrict__ batch,
                                                        int n) {
    int t = threadIdx.x;
    int sub = t >> 3, lane = t & 7;       // 32 nodes/block, 8 lanes/node
    int node = blockIdx.x * 32 + sub;
    bool act = node < n;
    int beg = 0, end = 0;
    float aldv = 0.0f;
    if (act) { beg = rowptr[node]; end = rowptr[node + 1]; aldv = ald[node]; }
    const unsigned short* hb = h16 + lane * 8;

    float acc[8] = {};
    float sm = 0.0f;
    int j = beg;
    if (j + 4 <= end) {
        int s0 = srcs[j], s1 = srcs[j + 1], s2 = srcs[j + 2], s3 = srcs[j + 3];
        for (; j + 8 <= end; j += 4) {
            // prefetch next quad's indices: breaks srcs->gather serial chain
            int n0 = srcs[j + 4], n1 = srcs[j + 5];
            int n2 = srcs[j + 6], n3 = srcs[j + 7];
            float e0 = als[s0] + aldv, e1 = als[s1] + aldv;
            float e2 = als[s2] + aldv, e3 = als[s3] + aldv;
            uint4 q0 = *(const uint4*)(hb + (size_t)s0 * 64);
            uint4 q1 = *(const uint4*)(hb + (size_t)s1 * 64);
            uint4 q2 = *(const uint4*)(hb + (size_t)s2 * 64);
            uint4 q3 = *(const uint4*)(hb + (size_t)s3 * 64);
            e0 = (e0 >= 0.0f) ? e0 : 0.2f * e0;
            e1 = (e1 >= 0.0f) ? e1 : 0.2f * e1;
            e2 = (e2 >= 0.0f) ? e2 : 0.2f * e2;
            e3 = (e3 >= 0.0f) ? e3 : 0.2f * e3;
            float w0 = __expf(e0), w1 = __expf(e1);
            float w2 = __expf(e2), w3 = __expf(e3);
            sm += (w0 + w1) + (w2 + w3);
            bf8_fma(acc, q0, w0);
            bf8_fma(acc, q1, w1);
            bf8_fma(acc, q2, w2);
            bf8_fma(acc, q3, w3);
            s0 = n0; s1 = n1; s2 = n2; s3 = n3;
        }
        // final full quad (s0..s3 already loaded)
        {
            float e0 = als[s0] + aldv, e1 = als[s1] + aldv;
            float e2 = als[s2] + aldv, e3 = als[s3] + aldv;
            uint4 q0 = *(const uint4*)(hb + (size_t)s0 * 64);
            uint4 q1 = *(const uint4*)(hb + (size_t)s1 * 64);
            uint4 q2 = *(const uint4*)(hb + (size_t)s2 * 64);
            uint4 q3 = *(const uint4*)(hb + (size_t)s3 * 64);
            e0 = (e0 >= 0.0f) ? e0 : 0.2f * e0;
            e1 = (e1 >= 0.0f) ? e1 : 0.2f * e1;
            e2 = (e2 >= 0.0f) ? e2 : 0.2f * e2;
            e3 = (e3 >= 0.0f) ? e3 : 0.2f * e3;
            float w0 = __expf(e0), w1 = __expf(e1);
            float w2 = __expf(e2), w3 = __expf(e3);
            sm += (w0 + w1) + (w2 + w3);
            bf8_fma(acc, q0, w0);
            bf8_fma(acc, q1, w1);
            bf8_fma(acc, q2, w2);
            bf8_fma(acc, q3, w3);
            j += 4;
        }
    }
    for (; j < end; j++) {
        int s = srcs[j];
        float e = als[s] + aldv;
        e = (e >= 0.0f) ? e : 0.2f * e;
        float w = __expf(e);
        uint4 q = *(const uint4*)(hb + (size_t)s * 64);
        sm += w;
        bf8_fma(acc, q, w);
    }

    float inv = 1.0f / (sm + 1e-16f);
    if (!POOL) {
        if (act) {
            float* op = hout + (size_t)node * 64 + lane * 8;
            *(float4*)op = make_float4(acc[0] * inv, acc[1] * inv, acc[2] * inv, acc[3] * inv);
            *(float4*)(op + 4) = make_float4(acc[4] * inv, acc[5] * inv, acc[6] * inv, acc[7] * inv);
        }
    } else {
        float o[8];
#pragma unroll
        for (int k = 0; k < 8; k++) o[k] = act ? acc[k] * inv : 0.0f;
        int d0 = blockIdx.x * 32;
        int gF = batch[d0];                               // d0 < n for all blocks
        int gL = batch[(d0 + 31 < n) ? d0 + 31 : n - 1];
        __shared__ float red[4][64];
        if (gF == gL) {
            // uniform block: shuffle-reduce across the wave's 8 subs
#pragma unroll
            for (int k = 0; k < 8; k++) {
                o[k] += __shfl_xor(o[k], 8);
                o[k] += __shfl_xor(o[k], 16);
                o[k] += __shfl_xor(o[k], 32);
            }
            int wv = t >> 6;
            if ((t & 56) == 0) {                          // one sub per wave holds sums
#pragma unroll
                for (int k = 0; k < 8; k++) red[wv][lane * 8 + k] = o[k];
            }
            __syncthreads();
            if (t < 64) {
                float s = red[0][t] + red[1][t] + red[2][t] + red[3][t];
                atomicAdd(&gsum[gF * 64 + t], s);
            }
        } else {
            // graph-boundary block (~8%): per-thread global atomics
            int myg = act ? batch[node] : gF;
#pragma unroll
            for (int k = 0; k < 8; k++)
                atomicAdd(&gsum[myg * 64 + lane * 8 + k], o[k]);
        }
    }
}

// --- tiny FC over fused per-graph sums: one wave per graph ------------------
__global__ __launch_bounds__(64) void fc_small(const float* __restrict__ gsum,
                                               const float* __restrict__ b2,
                                               const int* __restrict__ batch,
                                               const float* __restrict__ fcW,
                                               const float* __restrict__ fcb,
                                               float* __restrict__ out, int n) {
    int g = blockIdx.x;
    int t = threadIdx.x;   // 0..63
    __shared__ int sLo, sHi;
    if (t == 0) {
        int lo = 0, hi = n;
        while (lo < hi) { int m = (lo + hi) >> 1; if (batch[m] < g) lo = m + 1; else hi = m; }
        sLo = lo;
    } else if (t == 1) {
        int lo = 0, hi = n;
        while (lo < hi) { int m = (lo + hi) >> 1; if (batch[m] < g + 1) lo = m + 1; else hi = m; }
        sHi = lo;
    }
    __syncthreads();
    float c = (float)(sHi - sLo);
    float s = gsum[g * 64 + t] + c * b2[t];
    float cd = (c > 1.0f) ? c : 1.0f;
    float p = s / cd;
    float s0 = p * fcW[t * 2 + 0];
    float s1 = p * fcW[t * 2 + 1];
#pragma unroll
    for (int o = 32; o; o >>= 1) {
        s0 += __shfl_xor(s0, o);
        s1 += __shfl_xor(s1, o);
    }
    if (t == 0) {
        out[g * 2 + 0] = s0 + fcb[0];
        out[g * 2 + 1] = s1 + fcb[1];
    }
}

extern "C" void kernel_launch(void* const* d_in, const int* in_sizes, int n_in,
                              void* d_out, int out_size, void* d_ws, size_t ws_size,
                              hipStream_t stream) {
    const float* x    = (const float*)d_in[0];
    const int*   ei   = (const int*)d_in[1];
    const int*   batch= (const int*)d_in[2];
    const float* W1   = (const float*)d_in[3];
    const float* as1  = (const float*)d_in[4];
    const float* ad1  = (const float*)d_in[5];
    const float* b1   = (const float*)d_in[6];
    const float* W2   = (const float*)d_in[7];
    const float* as2  = (const float*)d_in[8];
    const float* ad2  = (const float*)d_in[9];
    const float* b2   = (const float*)d_in[10];
    const float* fcW  = (const float*)d_in[11];
    const float* fcb  = (const float*)d_in[12];
    float* out = (float*)d_out;

    const int N = in_sizes[2];       // 100000
    const int E = in_sizes[1] / 2;   // 1600000
    const int G = out_size / 2;      // 256
    const int tot = E + N;
    const int NB = (N + NPB - 1) / NPB;   // 391 buckets

    // ws layout (~46.5 MiB): pairs ALIASES bufO (disjoint lifetimes:
    // pairs die at build_csr; bufO first written by aggregate layer 1).
    float* ws     = (float*)d_ws;
    float* bufO   = ws;                                  // N*64 fp32  25.6 MB
    unsigned int* pairs  = (unsigned int*)bufO;          // alias      7.2 MB
    float* als    = bufO + (size_t)N * 64;               // N          0.4 MB
    float* ald    = als + N;                             // N          0.4 MB
    int*   rowptr = (int*)(ald + N);                     // N+1        0.4 MB
    int*   srcs   = rowptr + N + 1;                      // tot        6.8 MB
    int*   bcur   = srcs + tot;                          // NB
    unsigned short* bufH16 = (unsigned short*)(bcur + NB);  // N*64   12.8 MB
    float* gsum   = (float*)(bufH16 + (size_t)N * 64);   // G*64       64 KB

    dim3 b256(256);
    int gsElems = G * 64;
    int gInit = (max(NB, gsElems) + 255) / 256;
    int gPart = (E + EPB - 1) / EPB;
    int gGemm = (N + 63) / 64;
    int gAgg  = (N + 31) / 32;

    // ---- CSR build: partition + fused sort/fill -----------------------------
    init_all<<<gInit, b256, 0, stream>>>(bcur, NB, gsum, gsElems);
    partition<<<gPart, b256, 0, stream>>>(ei, E, NB, bcur, pairs);
    build_csr<<<NB, b256, 0, stream>>>(pairs, bcur, N, NB, rowptr, srcs);

    // ---- layer 1 ----
    node_gemm<72><<<gGemm, b256, 0, stream>>>(x, W1, as1, ad1, nullptr, 0.0f,
                                              bufH16, als, ald, N);
    gat_aggregate<false><<<gAgg, b256, 0, stream>>>(rowptr, srcs, als, ald,
                                                    bufH16, bufO, nullptr, nullptr, N);

    // ---- layer 2 (input = leaky(bufO + b1, 0.01)); pool fused in -----------
    node_gemm<64><<<gGemm, b256, 0, stream>>>(bufO, W2, as2, ad2, b1, 0.01f,
                                              bufH16, als, ald, N);
    gat_aggregate<true><<<gAgg, b256, 0, stream>>>(rowptr, srcs, als, ald,
                                                   bufH16, nullptr, gsum, batch, N);

    // ---- tiny FC over per-graph sums ----
    fc_small<<<G, dim3(64), 0, stream>>>(gsum, b2, batch, fcW, fcb, out, N);
}

// Round 9
// 317.520 us; speedup vs baseline: 1.2964x; 1.1141x over previous
//
#include <hip/hip_runtime.h>
#include <hip/hip_bf16.h>
#include <math.h>

// ---------------------------------------------------------------------------
// GAT: 2x GATConv(heads=1) + global mean pool + FC(64->2)
// R21 = exact R17 revert (best: 331.0us) + ONE isolated change:
//       float4-vectorized x staging in node_gemm (was scalar 4B/lane).
//   R19/R20 post-mortem: the depth-4 aggregate loop at 32 VGPR is on a
//   codegen knife-edge -- ANY added live state in that kernel (depth-8,
//   POOL template epilogue) tips the allocator into scratch spill
//   (WRITE 25->95/16.6MB, 2x dur). Aggregate is therefore byte-identical
//   to R17: early-return, no template, no LDS, no extra params.
// (Resubmission: Round 8 failed with GPUAcquisitionTimeout before running.)
// ---------------------------------------------------------------------------

#define NPB 256          // nodes per bucket
#define EPB 4096         // edges per partition block (256 thr x 16)
#define PSTRIDE 4608     // slots per bucket (lambda=4092, +8 sigma)
#define XPAD 68          // xs leading-dim pad: 8-way banks, 16B-aligned rows

__device__ __forceinline__ unsigned int f2bf(float v) {
    unsigned int b = __float_as_uint(v);
    b += 0x7FFFu + ((b >> 16) & 1u);   // round-to-nearest-even
    return b >> 16;
}

// --- init: zero bucket cursors ----------------------------------------------
__global__ __launch_bounds__(256) void init_all(int* __restrict__ bcur, int NB) {
    int i = blockIdx.x * 256 + threadIdx.x;
    if (i < NB) bcur[i] = 0;
}

// --- partition edges into fixed-stride dst-buckets (packed uint32) ----------
__global__ __launch_bounds__(256) void partition(const int* __restrict__ ei,
                                                 int E, int NB,
                                                 int* __restrict__ bcur,
                                                 unsigned int* __restrict__ pairs) {
    __shared__ int h[512];
    __shared__ int hb[512];
    int t = threadIdx.x;
    for (int i = t; i < 512; i += 256) h[i] = 0;
    __syncthreads();
    int i0 = blockIdx.x * EPB;
    unsigned int val[16];
    int bk[16], r[16];
#pragma unroll
    for (int k = 0; k < 16; k++) {
        int i = i0 + k * 256 + t;
        bk[k] = -1;
        if (i < E) {
            int s = ei[i];
            int d = ei[E + i];
            bk[k] = d >> 8;
            val[k] = (unsigned)s | ((unsigned)(d & 255) << 24);
            r[k] = atomicAdd(&h[bk[k]], 1);
        }
    }
    __syncthreads();
    for (int b = t; b < NB; b += 256)
        hb[b] = h[b] ? atomicAdd(&bcur[b], h[b]) : 0;
    __syncthreads();
#pragma unroll
    for (int k = 0; k < 16; k++) {
        if (bk[k] < 0) continue;
        int pos = hb[bk[k]] + r[k];
        if (pos < PSTRIDE)                 // overflow guard (stat. impossible)
            pairs[(size_t)bk[k] * PSTRIDE + pos] = val[k];
    }
}

// --- per-bucket CSR fill with FUSED counting sort by src>>9 -----------------
// Sort in LDS (Q), then degree/scan/fill directly from Q. Each node's CSR
// list fills ~ascending in src, so all co-resident aggregate blocks sweep
// h16 through a moving window (convoy; cut FETCH 172->162MB, dur -4us).
__global__ __launch_bounds__(256) void build_csr(const unsigned int* __restrict__ pairs,
                                                 const int* __restrict__ bcur,
                                                 int n, int NB,
                                                 int* __restrict__ rowptr,
                                                 int* __restrict__ srcs) {
    int b = blockIdx.x, t = threadIdx.x;
    __shared__ int c[512];
    __shared__ int s2[256];
    __shared__ int sbase, stot;
    __shared__ unsigned int Q[PSTRIDE];   // 18.4 KB sorted bucket
    __shared__ int hist[256];
    __shared__ int hcur[256];
    // ---- global bucket-count scan (for CSR base offset) ----
    int c0 = (2 * t < NB) ? min(bcur[2 * t], PSTRIDE) : 0;
    int c1 = (2 * t + 1 < NB) ? min(bcur[2 * t + 1], PSTRIDE) : 0;
    c[2 * t] = c0; c[2 * t + 1] = c1;
    s2[t] = c0 + c1;
    hist[t] = 0;
    __syncthreads();
    for (int o = 1; o < 256; o <<= 1) {
        int u = (t >= o) ? s2[t - o] : 0;
        __syncthreads();
        s2[t] += u;
        __syncthreads();
    }
    if (t == 0) {
        int p = b >> 1;
        int ex = s2[p] - (c[2 * p] + c[2 * p + 1]);
        sbase = ex + ((b & 1) ? c[b & ~1] : 0);
        stot = s2[255];
    }
    __syncthreads();
    int d0 = b << 8;
    int nb = min(NPB, n - d0);
    int cnt_b = c[b];
    int csr0 = sbase + d0;   // pairs before + one self-loop per node before
    const unsigned int* pb = pairs + (size_t)b * PSTRIDE;

    // ---- counting sort by src>>9 into Q ----
    for (int j = t; j < cnt_b; j += 256)
        atomicAdd(&hist[(pb[j] & 0xFFFFFFu) >> 9], 1);   // key <= 195
    __syncthreads();
    int hv = hist[t];
    hcur[t] = hv;
    __syncthreads();
    for (int o = 1; o < 256; o <<= 1) {
        int u = (t >= o) ? hcur[t - o] : 0;
        __syncthreads();
        hcur[t] += u;
        __syncthreads();
    }
    hcur[t] -= hv;                        // exclusive base -> cursor
    __syncthreads();
    for (int j = t; j < cnt_b; j += 256) {
        unsigned int p = pb[j];
        int pos = atomicAdd(&hcur[(p & 0xFFFFFFu) >> 9], 1);
        Q[pos] = p;
    }
    __syncthreads();

    // ---- degree count / scan / fill from sorted Q ----
    __shared__ int deg[NPB];
    __shared__ int cur[NPB];
    __shared__ int tmp[NPB];
    deg[t] = (t < nb) ? 1 : 0;   // self-loop
    __syncthreads();
    for (int j = t; j < cnt_b; j += 256)
        atomicAdd(&deg[Q[j] >> 24], 1);
    __syncthreads();
    int v = deg[t];
    tmp[t] = v;
    __syncthreads();
    for (int o = 1; o < NPB; o <<= 1) {
        int u = (t >= o) ? tmp[t - o] : 0;
        __syncthreads();
        tmp[t] += u;
        __syncthreads();
    }
    int excl = tmp[t] - v;
    if (t < nb) {
        rowptr[d0 + t] = csr0 + excl;
        srcs[csr0 + excl] = d0 + t;   // self-loop at slot 0
        cur[t] = excl + 1;
    }
    __syncthreads();
    // j-round order over sorted Q -> each node's list fills ~ascending in src
    for (int j = t; j < cnt_b; j += 256) {
        unsigned int p = Q[j];
        int off = atomicAdd(&cur[p >> 24], 1);
        srcs[csr0 + off] = (int)(p & 0x00FFFFFFu);
    }
    if (b == 0 && t == 0) rowptr[n] = n + stot;
}

// --- tiled node GEMM: 64 nodes x 64 cols per block, 4x4 per thread ----------
// R21: x staging vectorized to float4 (16B/lane); a float4 never straddles
// the lim boundary (IN_DIM % 4 == 0, lim is a multiple of IN_DIM).
template <int IN_DIM>
__global__ __launch_bounds__(256) void node_gemm(const float* __restrict__ x,
                                                 const float* __restrict__ W,
                                                 const float* __restrict__ a_src,
                                                 const float* __restrict__ a_dst,
                                                 const float* __restrict__ bias_in,
                                                 float slope_in,
                                                 unsigned short* __restrict__ h16,
                                                 float* __restrict__ al_s,
                                                 float* __restrict__ al_d,
                                                 int n) {
    __shared__ float Ws[IN_DIM * 64];
    __shared__ float xs[IN_DIM][XPAD];
    int t = threadIdx.x;
    int nbase = blockIdx.x * 64;

    for (int idx = t; idx < IN_DIM * 16; idx += 256)
        ((float4*)Ws)[idx] = ((const float4*)W)[idx];
    const float* xb = x + (size_t)nbase * IN_DIM;
    int lim = min(64, n - nbase) * IN_DIM;           // in floats
    constexpr int NV = (64 * IN_DIM) / 4;            // float4 elements
    for (int idx = t; idx < NV; idx += 256) {
        int f0 = idx * 4;
        float4 v = make_float4(0.0f, 0.0f, 0.0f, 0.0f);
        if (f0 < lim) v = ((const float4*)xb)[idx];  // coalesced 16B/lane
        int node = f0 / IN_DIM;
        int k = f0 - node * IN_DIM;
        if (bias_in) {
            v.x += bias_in[k + 0];
            v.y += bias_in[k + 1];
            v.z += bias_in[k + 2];
            v.w += bias_in[k + 3];
            v.x = (v.x >= 0.0f) ? v.x : slope_in * v.x;
            v.y = (v.y >= 0.0f) ? v.y : slope_in * v.y;
            v.z = (v.z >= 0.0f) ? v.z : slope_in * v.z;
            v.w = (v.w >= 0.0f) ? v.w : slope_in * v.w;
        }
        xs[k + 0][node] = v.x;
        xs[k + 1][node] = v.y;
        xs[k + 2][node] = v.z;
        xs[k + 3][node] = v.w;
    }
    __syncthreads();

    int cg = t & 15;    // col group: cols 4cg..4cg+3
    int ng = t >> 4;    // node group: nodes 4ng..4ng+3
    float acc[4][4] = {};
#pragma unroll 8
    for (int k = 0; k < IN_DIM; k++) {
        float4 xv = *(const float4*)&xs[k][ng * 4];
        float4 wv = *(const float4*)&Ws[k * 64 + cg * 4];
        float xa[4] = {xv.x, xv.y, xv.z, xv.w};
        float wa[4] = {wv.x, wv.y, wv.z, wv.w};
#pragma unroll
        for (int i = 0; i < 4; i++)
#pragma unroll
            for (int j = 0; j < 4; j++)
                acc[i][j] += xa[i] * wa[j];
    }

    float4 as4 = *(const float4*)(a_src + cg * 4);
    float4 ad4 = *(const float4*)(a_dst + cg * 4);
#pragma unroll
    for (int i = 0; i < 4; i++) {
        int node = nbase + ng * 4 + i;
        if (node < n) {
            uint2 p;
            p.x = f2bf(acc[i][0]) | (f2bf(acc[i][1]) << 16);
            p.y = f2bf(acc[i][2]) | (f2bf(acc[i][3]) << 16);
            *(uint2*)(h16 + (size_t)node * 64 + cg * 4) = p;
        }
        float vs = acc[i][0] * as4.x + acc[i][1] * as4.y +
                   acc[i][2] * as4.z + acc[i][3] * as4.w;
        float vd = acc[i][0] * ad4.x + acc[i][1] * ad4.y +
                   acc[i][2] * ad4.z + acc[i][3] * ad4.w;
#pragma unroll
        for (int o = 8; o; o >>= 1) {
            vs += __shfl_xor(vs, o);
            vd += __shfl_xor(vd, o);
        }
        if (cg == 0 && node < n) { al_s[node] = vs; al_d[node] = vd; }
    }
}

// --- single-pass aggregate (R17 proven body, BYTE-IDENTICAL): ---------------
// 8 lanes/node, depth-4 prefetch. 53.4us / 32 VGPR / no spill.
// out[node] = (sum_j exp(e_j)*h[src_j]) / (sum_j exp(e_j) + 1e-16)
__device__ __forceinline__ void bf8_fma(float* acc, uint4 q, float w) {
    acc[0] += w * __uint_as_float(q.x << 16);
    acc[1] += w * __uint_as_float(q.x & 0xFFFF0000u);
    acc[2] += w * __uint_as_float(q.y << 16);
    acc[3] += w * __uint_as_float(q.y & 0xFFFF0000u);
    acc[4] += w * __uint_as_float(q.z << 16);
    acc[5] += w * __uint_as_float(q.z & 0xFFFF0000u);
    acc[6] += w * __uint_as_float(q.w << 16);
    acc[7] += w * __uint_as_float(q.w & 0xFFFF0000u);
}

__global__ __launch_bounds__(256) void gat_aggregate(const int* __restrict__ rowptr,
                                                     const int* __restrict__ srcs,
                                                     const float* __restrict__ als,
                                                     const float* __restrict__ ald,
                                                     const unsigned short* __restrict__ h16,
                                                     float* __restrict__ hout,
                                                     int n) {
    int t = threadIdx.x;
    int sub = t >> 3, lane = t & 7;       // 32 nodes/block, 8 lanes/node
    int node = blockIdx.x * 32 + sub;
    if (node >= n) return;
    int beg = rowptr[node], end = rowptr[node + 1];
    float aldv = ald[node];
    const unsigned short* hb = h16 + lane * 8;

    float acc[8] = {};
    float sm = 0.0f;
    int j = beg;
    if (j + 4 <= end) {
        int s0 = srcs[j], s1 = srcs[j + 1], s2 = srcs[j + 2], s3 = srcs[j + 3];
        for (; j + 8 <= end; j += 4) {
            // prefetch next quad's indices: breaks srcs->gather serial chain
            int n0 = srcs[j + 4], n1 = srcs[j + 5];
            int n2 = srcs[j + 6], n3 = srcs[j + 7];
            float e0 = als[s0] + aldv, e1 = als[s1] + aldv;
            float e2 = als[s2] + aldv, e3 = als[s3] + aldv;
            uint4 q0 = *(const uint4*)(hb + (size_t)s0 * 64);
            uint4 q1 = *(const uint4*)(hb + (size_t)s1 * 64);
            uint4 q2 = *(const uint4*)(hb + (size_t)s2 * 64);
            uint4 q3 = *(const uint4*)(hb + (size_t)s3 * 64);
            e0 = (e0 >= 0.0f) ? e0 : 0.2f * e0;
            e1 = (e1 >= 0.0f) ? e1 : 0.2f * e1;
            e2 = (e2 >= 0.0f) ? e2 : 0.2f * e2;
            e3 = (e3 >= 0.0f) ? e3 : 0.2f * e3;
            float w0 = __expf(e0), w1 = __expf(e1);
            float w2 = __expf(e2), w3 = __expf(e3);
            sm += (w0 + w1) + (w2 + w3);
            bf8_fma(acc, q0, w0);
            bf8_fma(acc, q1, w1);
            bf8_fma(acc, q2, w2);
            bf8_fma(acc, q3, w3);
            s0 = n0; s1 = n1; s2 = n2; s3 = n3;
        }
        // final full quad (s0..s3 already loaded)
        {
            float e0 = als[s0] + aldv, e1 = als[s1] + aldv;
            float e2 = als[s2] + aldv, e3 = als[s3] + aldv;
            uint4 q0 = *(const uint4*)(hb + (size_t)s0 * 64);
            uint4 q1 = *(const uint4*)(hb + (size_t)s1 * 64);
            uint4 q2 = *(const uint4*)(hb + (size_t)s2 * 64);
            uint4 q3 = *(const uint4*)(hb + (size_t)s3 * 64);
            e0 = (e0 >= 0.0f) ? e0 : 0.2f * e0;
            e1 = (e1 >= 0.0f) ? e1 : 0.2f * e1;
            e2 = (e2 >= 0.0f) ? e2 : 0.2f * e2;
            e3 = (e3 >= 0.0f) ? e3 : 0.2f * e3;
            float w0 = __expf(e0), w1 = __expf(e1);
            float w2 = __expf(e2), w3 = __expf(e3);
            sm += (w0 + w1) + (w2 + w3);
            bf8_fma(acc, q0, w0);
            bf8_fma(acc, q1, w1);
            bf8_fma(acc, q2, w2);
            bf8_fma(acc, q3, w3);
            j += 4;
        }
    }
    for (; j < end; j++) {
        int s = srcs[j];
        float e = als[s] + aldv;
        e = (e >= 0.0f) ? e : 0.2f * e;
        float w = __expf(e);
        uint4 q = *(const uint4*)(hb + (size_t)s * 64);
        sm += w;
        bf8_fma(acc, q, w);
    }

    float inv = 1.0f / (sm + 1e-16f);
    float4 o0 = make_float4(acc[0] * inv, acc[1] * inv, acc[2] * inv, acc[3] * inv);
    float4 o1 = make_float4(acc[4] * inv, acc[5] * inv, acc[6] * inv, acc[7] * inv);
    float* op = hout + (size_t)node * 64 + lane * 8;
    *(float4*)op = o0;
    *(float4*)(op + 4) = o1;
}

// --- fused pool + FC: one block per graph, binary-search batch bounds -------
__global__ __launch_bounds__(256) void pool_fc(const float* __restrict__ hout,
                                               const float* __restrict__ b2,
                                               const int* __restrict__ batch,
                                               const float* __restrict__ fcW,
                                               const float* __restrict__ fcb,
                                               float* __restrict__ out, int n) {
    int g = blockIdx.x;
    int t = threadIdx.x;
    __shared__ int sLo, sHi;
    __shared__ float red[4][64];
    if (t == 0) {
        int lo = 0, hi = n;
        while (lo < hi) { int m = (lo + hi) >> 1; if (batch[m] < g) lo = m + 1; else hi = m; }
        sLo = lo;
    } else if (t == 64) {
        int lo = 0, hi = n;
        while (lo < hi) { int m = (lo + hi) >> 1; if (batch[m] < g + 1) lo = m + 1; else hi = m; }
        sHi = lo;
    }
    __syncthreads();
    int lo = sLo, hi = sHi;
    int wv = t >> 6, lane = t & 63;
    float acc = 0.0f;
    for (int node = lo + wv; node < hi; node += 4)
        acc += hout[(size_t)node * 64 + lane];
    red[wv][lane] = acc;
    __syncthreads();
    if (wv == 0) {
        float c = (float)(hi - lo);
        float s = red[0][lane] + red[1][lane] + red[2][lane] + red[3][lane];
        s += c * b2[lane];
        float cd = (c > 1.0f) ? c : 1.0f;
        float p = s / cd;
        float s0 = p * fcW[lane * 2 + 0];
        float s1 = p * fcW[lane * 2 + 1];
#pragma unroll
        for (int o = 32; o; o >>= 1) {
            s0 += __shfl_xor(s0, o);
            s1 += __shfl_xor(s1, o);
        }
        if (lane == 0) {
            out[g * 2 + 0] = s0 + fcb[0];
            out[g * 2 + 1] = s1 + fcb[1];
        }
    }
}

extern "C" void kernel_launch(void* const* d_in, const int* in_sizes, int n_in,
                              void* d_out, int out_size, void* d_ws, size_t ws_size,
                              hipStream_t stream) {
    const float* x    = (const float*)d_in[0];
    const int*   ei   = (const int*)d_in[1];
    const int*   batch= (const int*)d_in[2];
    const float* W1   = (const float*)d_in[3];
    const float* as1  = (const float*)d_in[4];
    const float* ad1  = (const float*)d_in[5];
    const float* b1   = (const float*)d_in[6];
    const float* W2   = (const float*)d_in[7];
    const float* as2  = (const float*)d_in[8];
    const float* ad2  = (const float*)d_in[9];
    const float* b2   = (const float*)d_in[10];
    const float* fcW  = (const float*)d_in[11];
    const float* fcb  = (const float*)d_in[12];
    float* out = (float*)d_out;

    const int N = in_sizes[2];       // 100000
    const int E = in_sizes[1] / 2;   // 1600000
    const int G = out_size / 2;      // 256
    const int tot = E + N;
    const int NB = (N + NPB - 1) / NPB;   // 391 buckets

    // ws layout (~46 MiB): pairs ALIASES bufO (disjoint lifetimes:
    // pairs die at build_csr; bufO first written by aggregate layer 1).
    float* ws     = (float*)d_ws;
    float* bufO   = ws;                                  // N*64 fp32  25.6 MB
    unsigned int* pairs  = (unsigned int*)bufO;          // alias      7.2 MB
    float* als    = bufO + (size_t)N * 64;               // N          0.4 MB
    float* ald    = als + N;                             // N          0.4 MB
    int*   rowptr = (int*)(ald + N);                     // N+1        0.4 MB
    int*   srcs   = rowptr + N + 1;                      // tot        6.8 MB
    int*   bcur   = srcs + tot;                          // NB
    unsigned short* bufH16 = (unsigned short*)(bcur + NB);  // N*64   12.8 MB

    dim3 b256(256);
    int gInit = (NB + 255) / 256;
    int gPart = (E + EPB - 1) / EPB;
    int gGemm = (N + 63) / 64;
    int gAgg  = (N + 31) / 32;

    // ---- CSR build: partition + fused sort/fill -----------------------------
    init_all<<<gInit, b256, 0, stream>>>(bcur, NB);
    partition<<<gPart, b256, 0, stream>>>(ei, E, NB, bcur, pairs);
    build_csr<<<NB, b256, 0, stream>>>(pairs, bcur, N, NB, rowptr, srcs);

    // ---- layer 1 ----
    node_gemm<72><<<gGemm, b256, 0, stream>>>(x, W1, as1, ad1, nullptr, 0.0f,
                                              bufH16, als, ald, N);
    gat_aggregate<<<gAgg, b256, 0, stream>>>(rowptr, srcs, als, ald, bufH16, bufO, N);

    // ---- layer 2 (input = leaky(bufO + b1, 0.01)) ----
    node_gemm<64><<<gGemm, b256, 0, stream>>>(bufO, W2, as2, ad2, b1, 0.01f,
                                              bufH16, als, ald, N);
    gat_aggregate<<<gAgg, b256, 0, stream>>>(rowptr, srcs, als, ald, bufH16, bufO, N);

    // ---- fused pool + fc ----
    pool_fc<<<G, b256, 0, stream>>>(bufO, b2, batch, fcW, fcb, out, N);
}